// Round 2
// baseline (558.607 us; speedup 1.0000x reference)
//
#include <hip/hip_runtime.h>
#include <math.h>

#define NNZ_C 3200000
#define NN_C  100000
#define NE_C  100000
#define KD    16
#define EPSF  1e-6f
#define LSEP  0.1f

// Workspace layout (float elements) — total 1,800,064 floats = 7.2 MB:
//   [0, NN_C)                      Dv   (node degree)
//   [NN_C, NN_C+NE_C)              De   (edge degree)
//   [OFF_S, OFF_S + NE_C*KD)       S    (edge accumulators, 100000 x 16)
//   [OFF_ACC, OFF_ACC+64)          acc: theta[0..15], fdvf[16..31],
//                                       posSum[32], negSum[33], posCnt[34], negCnt[35]
#define OFF_DV  0
#define OFF_DE  (NN_C)
#define OFF_S   (NN_C + NE_C)
#define OFF_ACC (OFF_S + NE_C * KD)
#define ZERO_FLOATS (OFF_ACC + 64)

// ---- K1: degree histograms -------------------------------------------------
// indices are int32 (harness converts integer inputs to int32)
__global__ __launch_bounds__(256) void k_hist(const int* __restrict__ il,
                                              float* __restrict__ Dv,
                                              float* __restrict__ De) {
    int p = blockIdx.x * 256 + threadIdx.x;
    if (p < NNZ_C) {
        int n = il[p];
        int e = il[NNZ_C + p];
        atomicAdd(&Dv[n], 1.0f);
        atomicAdd(&De[e], 1.0f);
    }
}

// ---- K2: f_Dv_f partials + separation stats (no nZ materialization) --------
__global__ __launch_bounds__(256) void k_norm(const float* __restrict__ Z,
                                              const float* __restrict__ Dv,
                                              float* __restrict__ acc) {
    __shared__ float sacc[KD + 4];
    int t = threadIdx.x;
    if (t < KD + 4) sacc[t] = 0.f;
    __syncthreads();

    int n = blockIdx.x * 256 + t;
    if (n < NN_C) {
        float dv = fmaxf(Dv[n], EPSF);       // clipped Dv
        const float4* z4 = (const float4*)(Z + (size_t)n * KD);
        float zr[KD];
        #pragma unroll
        for (int i = 0; i < 4; ++i) {
            float4 z = z4[i];
            zr[4*i+0] = z.x; zr[4*i+1] = z.y; zr[4*i+2] = z.z; zr[4*i+3] = z.w;
        }
        #pragma unroll
        for (int k = 0; k < KD; ++k) atomicAdd(&sacc[k], zr[k] * zr[k] * dv);
        float f = zr[0];
        if (f > 0.f)      { atomicAdd(&sacc[KD+0], f); atomicAdd(&sacc[KD+2], 1.f); }
        else if (f < 0.f) { atomicAdd(&sacc[KD+1], f); atomicAdd(&sacc[KD+3], 1.f); }
    }
    __syncthreads();
    if (t < KD)          atomicAdd(&acc[16 + t], sacc[t]);          // fdvf
    else if (t < KD + 4) atomicAdd(&acc[32 + (t - KD)], sacc[t]);   // sep stats
}

// ---- K3: scatter S[e,k] += Z[n,k] * rsqrt(Dv[n]) over all pins -------------
// thread -> (pin p, lane k); 16 consecutive threads share one pin, so the
// wave's 64 atomics cover 4 contiguous 64B rows of S.
__global__ __launch_bounds__(256) void k_scatter(const int* __restrict__ il,
                                                 const float* __restrict__ Z,
                                                 const float* __restrict__ Dv,
                                                 float* __restrict__ S) {
    unsigned int tid = blockIdx.x * 256u + threadIdx.x;
    if (tid < (unsigned int)NNZ_C * KD) {
        int p = (int)(tid >> 4);
        int k = (int)(tid & 15u);
        int n = il[p];
        int e = il[NNZ_C + p];
        float inv = rsqrtf(fmaxf(Dv[n], EPSF));
        float v = Z[(size_t)n * KD + k] * inv;
        atomicAdd(&S[(size_t)e * KD + k], v);
    }
}

// ---- K4: theta[k] = sum_e S[e,k]^2 / De[e] ---------------------------------
__global__ __launch_bounds__(256) void k_theta(const float* __restrict__ S,
                                               const float* __restrict__ De,
                                               float* __restrict__ acc) {
    __shared__ float sacc[KD];
    int t = threadIdx.x;
    if (t < KD) sacc[t] = 0.f;
    __syncthreads();

    int e = blockIdx.x * 256 + t;
    if (e < NE_C) {
        float rinv = 1.f / fmaxf(De[e], EPSF);
        const float4* s4 = (const float4*)(S + (size_t)e * KD);
        #pragma unroll
        for (int i = 0; i < 4; ++i) {
            float4 s = s4[i];
            atomicAdd(&sacc[4*i+0], s.x * s.x * rinv);
            atomicAdd(&sacc[4*i+1], s.y * s.y * rinv);
            atomicAdd(&sacc[4*i+2], s.z * s.z * rinv);
            atomicAdd(&sacc[4*i+3], s.w * s.w * rinv);
        }
    }
    __syncthreads();
    if (t < KD) atomicAdd(&acc[t], sacc[t]);
}

// ---- K5: finalize scalar loss ----------------------------------------------
__global__ void k_final(const float* __restrict__ acc, float* __restrict__ out) {
    if (blockIdx.x == 0 && threadIdx.x == 0) {
        float rsum = 0.f;
        #pragma unroll
        for (int k = 0; k < KD; ++k) {
            float theta = acc[k];
            float fd    = fmaxf(acc[16 + k], EPSF);
            float rq    = 1.f - theta / fd;
            if (!isfinite(rq)) rq = 0.f;
            rsum += rq;
        }
        float rl = rsum / (float)KD;
        float pS = acc[32], nS = acc[33], pC = acc[34], nC = acc[35];
        float pm = pS / fmaxf(pC, 1.f);
        float nm = nS / fmaxf(nC, 1.f);
        float sep = fabsf(pm - nm);
        float pen = (pC == 0.f || nC == 0.f) ? 1.f : 1.f / (sep + EPSF);
        out[0] = rl + LSEP * pen;
    }
}

extern "C" void kernel_launch(void* const* d_in, const int* in_sizes, int n_in,
                              void* d_out, int out_size, void* d_ws, size_t ws_size,
                              hipStream_t stream) {
    const float* Z  = (const float*)d_in[0];
    const int*   il = (const int*)d_in[1];   // (2, NNZ) delivered as int32
    float* ws  = (float*)d_ws;
    float* Dv  = ws + OFF_DV;
    float* De  = ws + OFF_DE;
    float* S   = ws + OFF_S;
    float* acc = ws + OFF_ACC;
    float* out = (float*)d_out;

    // zero Dv, De, S, acc
    hipMemsetAsync(ws, 0, (size_t)ZERO_FLOATS * sizeof(float), stream);

    k_hist<<<(NNZ_C + 255) / 256, 256, 0, stream>>>(il, Dv, De);
    k_norm<<<(NN_C + 255) / 256, 256, 0, stream>>>(Z, Dv, acc);
    {
        unsigned int total = (unsigned int)NNZ_C * KD;
        k_scatter<<<(total + 255) / 256, 256, 0, stream>>>(il, Z, Dv, S);
    }
    k_theta<<<(NE_C + 255) / 256, 256, 0, stream>>>(S, De, acc);
    k_final<<<1, 64, 0, stream>>>(acc, out);
}

// Round 3
// 313.733 us; speedup vs baseline: 1.7805x; 1.7805x over previous
//
#include <hip/hip_runtime.h>
#include <math.h>

#define NNZ_C 3200000
#define NN_C  100000
#define NE_C  100000
#define KD    16
#define EPSF  1e-6f
#define LSEP  0.1f

// Workspace layout (float/u32 elements) — total ~7.4 MB:
//   [0, 50000)               packed degree counters: DvPacked[25000] u32 (4 bins/word,
//                            8-bit each), then DePacked[25000]           (zeroed)
//   [50000, 50064)           acc: theta[0..15], fdvf[16..31],
//                            posSum[32], negSum[33], posCnt[34], negCnt[35] (zeroed)
//   [50064, 50064+1.6M)      S (edge accumulators, 100000 x 16)           (zeroed)
//   [OFF_DV, +100000)        Dv float (fully written by k_unpack, not zeroed)
//   [OFF_DE, +100000)        De float (fully written by k_unpack, not zeroed)
#define OFF_PK   0
#define OFF_ACC  50000
#define OFF_S    50064
#define OFF_DV   (OFF_S + NE_C * KD)
#define OFF_DE   (OFF_DV + NN_C)
#define ZERO_FLOATS OFF_DV   // zero packed + acc + S

// ---- K1a: privatized degree histograms (LDS byte-packed) --------------------
// 256 blocks: bit7 selects histogram (node/edge), bit6 selects 50K-bin range,
// bits[5:0] select the pin slice. 48.8KB LDS of u8x4-packed counters.
__global__ __launch_bounds__(256) void k_hist_lds(const int* __restrict__ il,
                                                  unsigned int* __restrict__ packed) {
    __shared__ unsigned int h[12500];
    int t = threadIdx.x;
    int b = blockIdx.x;
    int hist  = b >> 7;          // 0 -> Dv (node idx), 1 -> De (edge idx)
    int range = (b >> 6) & 1;    // bins [range*50000, +50000)
    int slice = b & 63;

    for (int w = t; w < 12500; w += 256) h[w] = 0u;
    __syncthreads();

    const int* idx = il + (size_t)hist * NNZ_C;
    unsigned int base = (unsigned int)range * 50000u;
    for (int p = slice * 256 + t; p < NNZ_C; p += 64 * 256) {
        unsigned int u = (unsigned int)idx[p] - base;
        if (u < 50000u) atomicAdd(&h[u >> 2], 1u << ((u & 3u) * 8u));
    }
    __syncthreads();

    unsigned int* gp = packed + hist * 25000 + range * 12500;
    for (int w = t; w < 12500; w += 256) {
        unsigned int v = h[w];
        if (v) atomicAdd(&gp[w], v);   // coalesced: 16 consecutive words = 1 line
    }
}

// ---- K1b: unpack byte counters -> float Dv, De ------------------------------
__global__ __launch_bounds__(256) void k_unpack(const unsigned int* __restrict__ packed,
                                                float* __restrict__ Dv,
                                                float* __restrict__ De) {
    int w = blockIdx.x * 256 + threadIdx.x;    // 0..49999 (words)
    if (w < 50000) {
        unsigned int v = packed[w];
        float4 f = make_float4((float)(v & 255u), (float)((v >> 8) & 255u),
                               (float)((v >> 16) & 255u), (float)(v >> 24));
        float* dst = (w < 25000) ? (Dv + (size_t)w * 4) : (De + (size_t)(w - 25000) * 4);
        *(float4*)dst = f;
    }
}

// ---- K2: f_Dv_f partials + separation stats ---------------------------------
__global__ __launch_bounds__(256) void k_norm(const float* __restrict__ Z,
                                              const float* __restrict__ Dv,
                                              float* __restrict__ acc) {
    __shared__ float sacc[KD + 4];
    int t = threadIdx.x;
    if (t < KD + 4) sacc[t] = 0.f;
    __syncthreads();

    int n = blockIdx.x * 256 + t;
    if (n < NN_C) {
        float dv = fmaxf(Dv[n], EPSF);
        const float4* z4 = (const float4*)(Z + (size_t)n * KD);
        float zr[KD];
        #pragma unroll
        for (int i = 0; i < 4; ++i) {
            float4 z = z4[i];
            zr[4*i+0] = z.x; zr[4*i+1] = z.y; zr[4*i+2] = z.z; zr[4*i+3] = z.w;
        }
        #pragma unroll
        for (int k = 0; k < KD; ++k) atomicAdd(&sacc[k], zr[k] * zr[k] * dv);
        float f = zr[0];
        if (f > 0.f)      { atomicAdd(&sacc[KD+0], f); atomicAdd(&sacc[KD+2], 1.f); }
        else if (f < 0.f) { atomicAdd(&sacc[KD+1], f); atomicAdd(&sacc[KD+3], 1.f); }
    }
    __syncthreads();
    if (t < KD)          atomicAdd(&acc[16 + t], sacc[t]);          // fdvf
    else if (t < KD + 4) atomicAdd(&acc[32 + (t - KD)], sacc[t]);   // sep stats
}

// ---- K3: scatter S[e,k] += Z[n,k] * rsqrt(Dv[n]) over all pins ---------------
__global__ __launch_bounds__(256) void k_scatter(const int* __restrict__ il,
                                                 const float* __restrict__ Z,
                                                 const float* __restrict__ Dv,
                                                 float* __restrict__ S) {
    unsigned int tid = blockIdx.x * 256u + threadIdx.x;
    if (tid < (unsigned int)NNZ_C * KD) {
        int p = (int)(tid >> 4);
        int k = (int)(tid & 15u);
        int n = il[p];
        int e = il[NNZ_C + p];
        float inv = rsqrtf(fmaxf(Dv[n], EPSF));
        float v = Z[(size_t)n * KD + k] * inv;
        atomicAdd(&S[(size_t)e * KD + k], v);
    }
}

// ---- K4: theta[k] = sum_e S[e,k]^2 / De[e] -----------------------------------
__global__ __launch_bounds__(256) void k_theta(const float* __restrict__ S,
                                               const float* __restrict__ De,
                                               float* __restrict__ acc) {
    __shared__ float sacc[KD];
    int t = threadIdx.x;
    if (t < KD) sacc[t] = 0.f;
    __syncthreads();

    int e = blockIdx.x * 256 + t;
    if (e < NE_C) {
        float rinv = 1.f / fmaxf(De[e], EPSF);
        const float4* s4 = (const float4*)(S + (size_t)e * KD);
        #pragma unroll
        for (int i = 0; i < 4; ++i) {
            float4 s = s4[i];
            atomicAdd(&sacc[4*i+0], s.x * s.x * rinv);
            atomicAdd(&sacc[4*i+1], s.y * s.y * rinv);
            atomicAdd(&sacc[4*i+2], s.z * s.z * rinv);
            atomicAdd(&sacc[4*i+3], s.w * s.w * rinv);
        }
    }
    __syncthreads();
    if (t < KD) atomicAdd(&acc[t], sacc[t]);
}

// ---- K5: finalize scalar loss -------------------------------------------------
__global__ void k_final(const float* __restrict__ acc, float* __restrict__ out) {
    if (blockIdx.x == 0 && threadIdx.x == 0) {
        float rsum = 0.f;
        #pragma unroll
        for (int k = 0; k < KD; ++k) {
            float theta = acc[k];
            float fd    = fmaxf(acc[16 + k], EPSF);
            float rq    = 1.f - theta / fd;
            if (!isfinite(rq)) rq = 0.f;
            rsum += rq;
        }
        float rl = rsum / (float)KD;
        float pS = acc[32], nS = acc[33], pC = acc[34], nC = acc[35];
        float pm = pS / fmaxf(pC, 1.f);
        float nm = nS / fmaxf(nC, 1.f);
        float sep = fabsf(pm - nm);
        float pen = (pC == 0.f || nC == 0.f) ? 1.f : 1.f / (sep + EPSF);
        out[0] = rl + LSEP * pen;
    }
}

extern "C" void kernel_launch(void* const* d_in, const int* in_sizes, int n_in,
                              void* d_out, int out_size, void* d_ws, size_t ws_size,
                              hipStream_t stream) {
    const float* Z  = (const float*)d_in[0];
    const int*   il = (const int*)d_in[1];   // (2, NNZ) delivered as int32
    float*        ws     = (float*)d_ws;
    unsigned int* packed = (unsigned int*)d_ws;
    float* acc = ws + OFF_ACC;
    float* S   = ws + OFF_S;
    float* Dv  = ws + OFF_DV;
    float* De  = ws + OFF_DE;
    float* out = (float*)d_out;

    // zero packed counters + acc + S (Dv/De fully overwritten by k_unpack)
    hipMemsetAsync(ws, 0, (size_t)ZERO_FLOATS * sizeof(float), stream);

    k_hist_lds<<<256, 256, 0, stream>>>(il, packed);
    k_unpack<<<(50000 + 255) / 256, 256, 0, stream>>>(packed, Dv, De);
    k_norm<<<(NN_C + 255) / 256, 256, 0, stream>>>(Z, Dv, acc);
    {
        unsigned int total = (unsigned int)NNZ_C * KD;
        k_scatter<<<(total + 255) / 256, 256, 0, stream>>>(il, Z, Dv, S);
    }
    k_theta<<<(NE_C + 255) / 256, 256, 0, stream>>>(S, De, acc);
    k_final<<<1, 64, 0, stream>>>(acc, out);
}